// Round 1
// 588.602 us; speedup vs baseline: 1.0886x; 1.0886x over previous
//
#include <hip/hip_runtime.h>
#include <math.h>

// clDice loss on MI355X (gfx950).
// soft_skeletonize = 20 iterations of:
//   m = minpool3(x); contour = relu(maxpool3(m) - m); x = relu(x - contour)
// Round-11: register-budget fix. Round-10 halved the VALU stream (packed
// f16) for only -17%, and VGPR_Count=64 while the steady-state live set is
// provably >=80 VGPRs (St = 20 regs/stage x K=4) -> allocator is cycling
// state through AGPRs/scratch every iteration (invisible in FETCH/WRITE:
// scratch is L2-resident). Grid gives only 4 blocks/CU = 4 waves/EU, so
// registers up to 128 are free. This round: amdgpu_waves_per_eu(4,4)
// (budget 128 VGPR, zero spills), #pragma unroll 2 on the pair loop
// (4 rows = lcm of x-ring period 4 and BUF period 2 -> ring movs vanish),
// and cross-iteration row prefetch (load y+2, consume y+1) so global-load
// latency spans a full iteration. Structure otherwise identical to the
// passing round-10 kernel: K=4 fused iterations/launch, z=32 grid,
// LDS edge exchange, 1 barrier per row-iter, 5 launches + finalize.

#define IMG_H 1024
#define IMG_W 1024
#define IMG_N (IMG_H * IMG_W)
#define NIMG  16
#define NZ    32                    // 16 pred + 16 gt images
#define BH    32                    // output rows per band
#define NBANDS (IMG_H / BH)         // 32
#define K     4                     // fused skeleton iterations per launch
#define EW    258                   // 256 lanes + 2 guard slots
#define NBLK  (NZ * NBANDS)         // 1024 blocks per launch
#define ITER_PAIRS ((BH + 6 * K) / 2)   // 28 pairs = 56 row-iterations

typedef _Float16 h2 __attribute__((ext_vector_type(2)));

__device__ __forceinline__ h2 hmin2(h2 a, h2 b) { return __builtin_elementwise_min(a, b); }
__device__ __forceinline__ h2 hmax2(h2 a, h2 b) { return __builtin_elementwise_max(a, b); }

union U32H { unsigned u; h2 h; };
__device__ __forceinline__ unsigned as_u(h2 h) { U32H t; t.h = h; return t.u; }
__device__ __forceinline__ h2 as_h2(unsigned u) { U32H t; t.u = u; return t.h; }

struct Hp { h2 lo, hi; };           // 4 image columns per lane
struct St { Hp hm1, hm2, m2, m3, q1, q2, x1, x2, x3, xc; };

// One pipeline stage. rmask: +inf pass / -inf force (maxpool row padding).
// Edge pair layout: e2[slot].x = {x_col0, m_col0} (read by LEFT-seeking
// neighbor at slot t+2); e2[slot].y = {x_col3, m_col3} (read at slot t).
template<int BUF>
__device__ __forceinline__ Hp stage_step(
    St& s, h2 rmask, int t, const uint2 (&e2)[2][EW])
{
    h2 lp = as_h2(e2[BUF][t].y);        // left nbr's col3 {x, m}
    h2 rp = as_h2(e2[BUF][t + 2].x);    // right nbr's col0 {x, m}
    // h-min3 of x row
    h2 midx = (h2){s.xc.lo[1], s.xc.hi[0]};               // {x1, x2}
    h2 hlo = hmin2(hmin2((h2){lp[0], s.xc.lo[0]}, s.xc.lo), midx);
    h2 hhi = hmin2(hmin2(midx, s.xc.hi), (h2){s.xc.hi[1], rp[0]});
    // v-min3 + row-validity mask
    h2 mlo = hmin2(hmin2(hmin2(s.hm1.lo, s.hm2.lo), hlo), rmask);
    h2 mhi = hmin2(hmin2(hmin2(s.hm1.hi, s.hm2.hi), hhi), rmask);
    // h-max3 of m (previous iter's m, in m2; neighbor edges from LDS)
    h2 midm = (h2){s.m2.lo[1], s.m2.hi[0]};
    h2 qlo = hmax2(hmax2((h2){lp[1], s.m2.lo[0]}, s.m2.lo), midm);
    h2 qhi = hmax2(hmax2(midm, s.m2.hi), (h2){s.m2.hi[1], rp[1]});
    // v-max3
    h2 Mlo = hmax2(hmax2(s.q1.lo, s.q2.lo), qlo);
    h2 Mhi = hmax2(hmax2(s.q1.hi, s.q2.hi), qhi);
    // contour + relu update
    const h2 Z2 = (h2){(_Float16)0.f, (_Float16)0.f};
    h2 elo = hmax2(s.x3.lo - hmax2(Mlo - s.m3.lo, Z2), Z2);
    h2 ehi = hmax2(s.x3.hi - hmax2(Mhi - s.m3.hi, Z2), Z2);
    // ring shifts
    s.hm1 = s.hm2; s.hm2.lo = hlo; s.hm2.hi = hhi;
    s.m3  = s.m2;  s.m2.lo  = mlo; s.m2.hi  = mhi;
    s.q1  = s.q2;  s.q2.lo  = qlo; s.q2.hi  = qhi;
    s.x3  = s.x2;  s.x2 = s.x1;    s.x1 = s.xc;
    Hp e; e.lo = elo; e.hi = ehi;
    return e;
}

// Load one input row (or +inf outside the image). FIRST launch reads the
// f32 source and converts; later launches read the f16 intermediate.
template<int FIRST>
__device__ __forceinline__ Hp load_row(
    int y, int c, const float* __restrict__ f32src,
    const unsigned short* __restrict__ bsrc)
{
    const _Float16 HINF = (_Float16)__builtin_huge_valf();
    Hp x; x.lo = (h2){HINF, HINF}; x.hi = (h2){HINF, HINF};
    if ((unsigned)y < (unsigned)IMG_H) {
        if constexpr (FIRST) {
            float4 f = *(const float4*)(f32src + (size_t)y * IMG_W + c);
            x.lo = (h2){(_Float16)f.x, (_Float16)f.y};
            x.hi = (h2){(_Float16)f.z, (_Float16)f.w};
        } else {
            uint2 u = *(const uint2*)(bsrc + (size_t)y * IMG_W + c);
            x.lo = as_h2(u.x);
            x.hi = as_h2(u.y);
        }
    }
    return x;
}

template<int BUF, int FIRST, int LAST>
__device__ __forceinline__ void iter_step(
    int y, int t, int c, int r0, St (&st)[K], Hp& xn,
    const float* __restrict__ f32src, const unsigned short* __restrict__ bsrc,
    unsigned short* __restrict__ bdst, const float* __restrict__ oth,
    float& a1, float& a2, uint2 (&e2)[K][2][EW])
{
    const _Float16 HINF = (_Float16)__builtin_huge_valf();
    const h2 PINF2 = (h2){HINF, HINF};
    const h2 NINF2 = (h2){-HINF, -HINF};

    // issue the row-(y+2) load now; its value is consumed NEXT iteration,
    // so the global-load latency spans a full iteration body.
    Hp tnext = load_row<FIRST>(y + 2, c, f32src, bsrc);

    __syncthreads();                         // prev-iter edge writes visible

    h2 rm = ((unsigned)(y - 13) < (unsigned)IMG_H) ? PINF2 : NINF2;
    Hp eK = stage_step<BUF>(st[K - 1], rm, t, e2[K - 1]);
    #pragma unroll
    for (int k = K - 2; k >= 0; --k) {
        rm = ((unsigned)(y - 4 * k - 1) < (unsigned)IMG_H) ? PINF2 : NINF2;
        Hp e = stage_step<BUF>(st[k], rm, t, e2[k]);
        h2 em = ((unsigned)(y - 4 * k - 3) < (unsigned)IMG_H) ? NINF2 : PINF2;
        st[k + 1].xc.lo = hmax2(e.lo, em);   // max(e,-inf)=e; max(e,+inf)=+inf
        st[k + 1].xc.hi = hmax2(e.hi, em);
    }
    st[0].xc = xn;                           // row y+1, loaded last iteration
    xn = tnext;

    // edge writes for next iteration (new xc + this iter's m, now in m2)
    #pragma unroll
    for (int k = 0; k < K; ++k) {
        e2[k][BUF ^ 1][t + 1] = make_uint2(
            as_u((h2){st[k].xc.lo[0], st[k].m2.lo[0]}),
            as_u((h2){st[k].xc.hi[1], st[k].m2.hi[1]}));
    }

    int orow = y - (4 * (K - 1) + 3);        // y - 15
    if ((unsigned)(orow - r0) < (unsigned)BH) {
        if constexpr (!LAST) {
            *(uint2*)(bdst + (size_t)orow * IMG_W + c) =
                make_uint2(as_u(eK.lo), as_u(eK.hi));
        } else {
            float4 ov = *(const float4*)(oth + (size_t)orow * IMG_W + c);
            float e0 = (float)eK.lo[0], e1 = (float)eK.lo[1];
            float e2f = (float)eK.hi[0], e3 = (float)eK.hi[1];
            a1 += e0 * ov.x + e1 * ov.y + e2f * ov.z + e3 * ov.w;
            a2 += e0 + e1 + e2f + e3;
        }
    }
}

template<int FIRST, int LAST>
__global__ __attribute__((amdgpu_waves_per_eu(4, 4)))
__launch_bounds__(256) void skel(
    const unsigned short* __restrict__ src, unsigned short* __restrict__ dst,
    const float* __restrict__ pred32, const float* __restrict__ gt32,
    double* __restrict__ partials)
{
    __shared__ uint2 e2[K][2][EW];    // {.x = col0 pair, .y = col3 pair}
    __shared__ double l1[4], l2[4];

    const int t = threadIdx.x, c = 4 * t;
    const int band = blockIdx.x, z = blockIdx.y;
    const int r0 = band * BH;
    const _Float16 HINF = (_Float16)__builtin_huge_valf();
    const h2 PINF2 = (h2){HINF, HINF};
    const h2 NINF2 = (h2){-HINF, -HINF};

    const float* f32src = (z < NIMG) ? pred32 + (size_t)z * IMG_N
                                     : gt32 + (size_t)(z - NIMG) * IMG_N;
    const unsigned short* bsrc = FIRST ? nullptr : src + (size_t)z * IMG_N;
    unsigned short* bdst = LAST ? nullptr : dst + (size_t)z * IMG_N;
    const float* oth = LAST ? ((z < NIMG) ? gt32 + (size_t)z * IMG_N
                                          : pred32 + (size_t)(z - NIMG) * IMG_N)
                            : nullptr;

    if (t < K) {
        #pragma unroll
        for (int b = 0; b < 2; ++b) {
            // guard pairs: x=+inf (0x7C00 low), m=-inf (0xFC00 high)
            e2[t][b][0]      = make_uint2(0u, 0xFC007C00u);  // only .y read
            e2[t][b][EW - 1] = make_uint2(0xFC007C00u, 0u);  // only .x read
        }
    }

    St st[K];
    #pragma unroll
    for (int k = 0; k < K; ++k) {
        st[k].hm1.lo = st[k].hm1.hi = PINF2;
        st[k].hm2.lo = st[k].hm2.hi = PINF2;
        st[k].m2.lo  = st[k].m2.hi  = NINF2;
        st[k].m3.lo  = st[k].m3.hi  = NINF2;
        st[k].q1.lo  = st[k].q1.hi  = NINF2;
        st[k].q2.lo  = st[k].q2.hi  = NINF2;
        st[k].x1.lo  = st[k].x1.hi  = PINF2;
        st[k].x2.lo  = st[k].x2.hi  = PINF2;
        st[k].x3.lo  = st[k].x3.hi  = PINF2;
        st[k].xc.lo  = st[k].xc.hi  = PINF2;
    }

    const int y0 = r0 - 2 * K;
    st[0].xc = load_row<FIRST>(y0, c, f32src, bsrc);
    Hp xn    = load_row<FIRST>(y0 + 1, c, f32src, bsrc);

    // prologue edge write into buf 0 (consumed by first iteration)
    #pragma unroll
    for (int k = 0; k < K; ++k) {
        e2[k][0][t + 1] = make_uint2(
            as_u((h2){st[k].xc.lo[0], st[k].m2.lo[0]}),
            as_u((h2){st[k].xc.hi[1], st[k].m2.hi[1]}));
    }

    float a1 = 0.f, a2 = 0.f;
    // unroll 2 pairs (4 rows) = lcm(x-ring period 4, LDS buf period 2):
    // all ring-shift register copies vanish at the loop back-edge.
    #pragma unroll 2
    for (int p = 0; p < ITER_PAIRS; ++p) {
        int y = y0 + 2 * p;
        iter_step<0, FIRST, LAST>(y,     t, c, r0, st, xn, f32src, bsrc, bdst, oth, a1, a2, e2);
        iter_step<1, FIRST, LAST>(y + 1, t, c, r0, st, xn, f32src, bsrc, bdst, oth, a1, a2, e2);
    }

    if constexpr (LAST) {                    // per-block partials (no atomics)
        double d1 = a1, d2 = a2;
        for (int off = 32; off; off >>= 1) {
            d1 += __shfl_down(d1, off);
            d2 += __shfl_down(d2, off);
        }
        const int w = t >> 6;
        if ((t & 63) == 0) { l1[w] = d1; l2[w] = d2; }
        __syncthreads();
        if (t == 0) {
            int bid = z * NBANDS + band;
            partials[2 * bid]     = l1[0] + l1[1] + l1[2] + l1[3];
            partials[2 * bid + 1] = l2[0] + l2[1] + l2[2] + l2[3];
        }
    }
}

__global__ __launch_bounds__(256) void finalize(
    const double* __restrict__ pp, float* __restrict__ out)
{
    __shared__ double sh[4][4];
    double i1 = 0, i2 = 0, t1 = 0, t2 = 0;
    for (int i = threadIdx.x; i < NBLK; i += 256) {
        double a = pp[2 * i], b = pp[2 * i + 1];
        if (i < NIMG * NBANDS) { i1 += a; i2 += b; }   // z < 16: cl_pred side
        else                   { t1 += a; t2 += b; }   // z >= 16: skel_gt side
    }
    for (int off = 32; off; off >>= 1) {
        i1 += __shfl_down(i1, off); i2 += __shfl_down(i2, off);
        t1 += __shfl_down(t1, off); t2 += __shfl_down(t2, off);
    }
    const int w = threadIdx.x >> 6;
    if ((threadIdx.x & 63) == 0) { sh[0][w] = i1; sh[1][w] = i2; sh[2][w] = t1; sh[3][w] = t2; }
    __syncthreads();
    if (threadIdx.x == 0) {
        double s1 = 0, s2 = 0, s3 = 0, s4 = 0;
        for (int j = 0; j < 4; ++j) { s1 += sh[0][j]; s2 += sh[1][j]; s3 += sh[2][j]; s4 += sh[3][j]; }
        double iflat = (s1 + 1.0) / (s2 + 1.0);
        double tflat = (s3 + 1.0) / (s4 + 1.0);
        out[0] = (float)(1.0 - 2.0 * (iflat * tflat) / (iflat + tflat));
    }
}

extern "C" void kernel_launch(void* const* d_in, const int* in_sizes, int n_in,
                              void* d_out, int out_size, void* d_ws, size_t ws_size,
                              hipStream_t stream)
{
    const float* pred = (const float*)d_in[0];
    const float* gt   = (const float*)d_in[1];

    unsigned short* A = (unsigned short*)d_ws;            // 32 f16 images (64 MiB)
    unsigned short* B = A + (size_t)NZ * IMG_N;           // 32 f16 images
    double* partials  = (double*)d_ws;                    // overlaps A; A is dead
                                                          // when launch 5 (reads B) runs
    dim3 grid(NBANDS, NZ);                                // 32 bands x 32 images

    skel<1, 0><<<grid, 256, 0, stream>>>(nullptr, A, pred, gt, nullptr);  // iters 1-4
    skel<0, 0><<<grid, 256, 0, stream>>>(A, B, pred, gt, nullptr);        // 5-8
    skel<0, 0><<<grid, 256, 0, stream>>>(B, A, pred, gt, nullptr);        // 9-12
    skel<0, 0><<<grid, 256, 0, stream>>>(A, B, pred, gt, nullptr);        // 13-16
    skel<0, 1><<<grid, 256, 0, stream>>>(B, nullptr, pred, gt, partials); // 17-20 + sums

    finalize<<<1, 256, 0, stream>>>(partials, (float*)d_out);
}